// Round 1
// baseline (78.329 us; speedup 1.0000x reference)
//
#include <hip/hip_runtime.h>

// Problem dims (fixed by setup_inputs)
#define BS     256
#define N_BAG  128
#define DXD    32
#define DYD    10
#define M_COMP 2048

#define TPB        256
#define MCHUNK     512              // m's per block
#define NBLK_PER_B (M_COMP / MCHUNK) // 4
#define LDA        36               // padded LDS row stride (floats), keeps 16B align

// ---------------- prep: b2[m] = ||c_x[m]||^2 ; yv2[m][d] = c_y^2 / sum(c_y^2) -------------
__global__ void prep_kernel(const float* __restrict__ c_x, const float* __restrict__ c_y,
                            float* __restrict__ b2, float* __restrict__ yv2) {
    int m = blockIdx.x * blockDim.x + threadIdx.x;
    if (m >= M_COMP) return;
    float s = 0.f;
#pragma unroll
    for (int k = 0; k < DXD; ++k) { float v = c_x[m * DXD + k]; s = fmaf(v, v, s); }
    b2[m] = s;
    float cy[DYD];
    float ny = 0.f;
#pragma unroll
    for (int d = 0; d < DYD; ++d) { cy[d] = c_y[m * DYD + d]; ny = fmaf(cy[d], cy[d], ny); }
    float inv = 1.0f / ny;  // (c_y/||c_y||)^2 = c_y^2 / sum(c_y^2)
#pragma unroll
    for (int d = 0; d < DYD; ++d) yv2[m * DYD + d] = cy[d] * cy[d] * inv;
}

// ---------------- main: per (b, m-chunk) partial reduction --------------------------------
__global__ __launch_bounds__(TPB) void main_kernel(
    const float* __restrict__ X,       // (BS, N_BAG, DXD)
    const float* __restrict__ sig_p,   // scalar
    const float* __restrict__ c_x,     // (M_COMP, DXD)
    const float* __restrict__ comp_w,  // (M_COMP,)
    const float* __restrict__ b2,      // (M_COMP,)
    const float* __restrict__ yv2,     // (M_COMP, DYD)
    float* __restrict__ part)          // (BS*NBLK_PER_B, 16): [0]=wsum, [1..10]=probs partial
{
    __shared__ float As[N_BAG][LDA];
    __shared__ float a2s[N_BAG];
    __shared__ float red[TPB / 64][DYD + 1];

    const int bid   = blockIdx.x;
    const int b     = bid >> 2;     // / NBLK_PER_B
    const int chunk = bid & 3;
    const int tid   = threadIdx.x;

    // Stage A-tile (128x32 fp32) + row norms into LDS
    if (tid < N_BAG) {
        const float* row = X + ((size_t)b * N_BAG + tid) * DXD;
        float a2 = 0.f;
#pragma unroll
        for (int j = 0; j < DXD / 4; ++j) {
            float4 v = ((const float4*)row)[j];
            *(float4*)&As[tid][4 * j] = v;
            a2 += v.x * v.x + v.y * v.y + v.z * v.z + v.w * v.w;
        }
        a2s[tid] = a2;
    }

    const float sgm    = fmaxf(sig_p[0], 1e-3f);
    const float inv_s2 = 1.0f / (sgm * sgm);

    const int m0 = chunk * MCHUNK + tid;  // two m's per thread
    const int m1 = m0 + TPB;

    float4 c0[8], c1[8];
#pragma unroll
    for (int j = 0; j < 8; ++j) {
        c0[j] = ((const float4*)(c_x + (size_t)m0 * DXD))[j];
        c1[j] = ((const float4*)(c_x + (size_t)m1 * DXD))[j];
    }
    const float b20 = b2[m0], b21 = b2[m1];
    float acc0 = 0.f, acc1 = 0.f;

    __syncthreads();

#pragma unroll 2
    for (int n = 0; n < N_BAG; ++n) {
        float dot0 = 0.f, dot1 = 0.f;
#pragma unroll
        for (int j = 0; j < 8; ++j) {
            float4 a = *(const float4*)&As[n][4 * j];  // broadcast across lanes
            dot0 = fmaf(a.x, c0[j].x, dot0);
            dot0 = fmaf(a.y, c0[j].y, dot0);
            dot0 = fmaf(a.z, c0[j].z, dot0);
            dot0 = fmaf(a.w, c0[j].w, dot0);
            dot1 = fmaf(a.x, c1[j].x, dot1);
            dot1 = fmaf(a.y, c1[j].y, dot1);
            dot1 = fmaf(a.z, c1[j].z, dot1);
            dot1 = fmaf(a.w, c1[j].w, dot1);
        }
        const float a2n = a2s[n];
        float d20 = fmaxf(fmaf(-2.f, dot0, a2n + b20), 0.f);
        float d21 = fmaxf(fmaf(-2.f, dot1, a2n + b21), 0.f);
        acc0 += __expf(-d20 * inv_s2);   // = K^2
        acc1 += __expf(-d21 * inv_s2);
    }

    const float ow0 = acc0 * comp_w[m0] * (1.0f / N_BAG);
    const float ow1 = acc1 * comp_w[m1] * (1.0f / N_BAG);

    float vals[DYD + 1];
    vals[0] = ow0 + ow1;
#pragma unroll
    for (int d = 0; d < DYD; ++d)
        vals[1 + d] = ow0 * yv2[(size_t)m0 * DYD + d] + ow1 * yv2[(size_t)m1 * DYD + d];

    // block reduction of 11 values: wave shuffle + cross-wave LDS
    const int lane = tid & 63, wv = tid >> 6;
#pragma unroll
    for (int v = 0; v < DYD + 1; ++v) {
        float x = vals[v];
#pragma unroll
        for (int off = 32; off > 0; off >>= 1) x += __shfl_down(x, off, 64);
        if (lane == 0) red[wv][v] = x;
    }
    __syncthreads();
    if (tid < DYD + 1) {
        float s = red[0][tid] + red[1][tid] + red[2][tid] + red[3][tid];
        part[bid * 16 + tid] = s;
    }
}

// ---------------- final: combine chunk partials, normalize --------------------------------
__global__ void final_kernel(const float* __restrict__ part, float* __restrict__ out) {
    int b = blockIdx.x * blockDim.x + threadIdx.x;
    if (b >= BS) return;
    const float* p = part + (size_t)b * NBLK_PER_B * 16;
    float denom = p[0] + p[16] + p[32] + p[48];
    denom       = (denom == 0.f) ? 1e-16f : denom;
    float invd  = 1.0f / denom;
#pragma unroll
    for (int d = 0; d < DYD; ++d) {
        float s = p[1 + d] + p[16 + 1 + d] + p[32 + 1 + d] + p[48 + 1 + d];
        out[(size_t)b * DYD + d] = s * invd;
    }
}

extern "C" void kernel_launch(void* const* d_in, const int* in_sizes, int n_in,
                              void* d_out, int out_size, void* d_ws, size_t ws_size,
                              hipStream_t stream) {
    const float* X      = (const float*)d_in[0];  // inputs (256,128,32)
    const float* sigma  = (const float*)d_in[1];  // scalar
    const float* c_x    = (const float*)d_in[2];  // (2048,32)
    const float* c_y    = (const float*)d_in[3];  // (2048,10)
    const float* comp_w = (const float*)d_in[4];  // (2048,)
    float*       out    = (float*)d_out;          // (256,10)

    float* ws   = (float*)d_ws;
    float* b2   = ws;                       // 2048 floats
    float* yv2  = ws + M_COMP;              // 2048*10 floats
    float* part = ws + M_COMP + M_COMP * DYD;  // 1024*16 floats

    prep_kernel<<<(M_COMP + 255) / 256, 256, 0, stream>>>(c_x, c_y, b2, yv2);
    main_kernel<<<BS * NBLK_PER_B, TPB, 0, stream>>>(X, sigma, c_x, comp_w, b2, yv2, part);
    final_kernel<<<1, 256, 0, stream>>>(part, out);
}

// Round 2
// 35.450 us; speedup vs baseline: 2.2096x; 2.2096x over previous
//
#include <hip/hip_runtime.h>

// Problem dims (fixed by setup_inputs)
#define BS     256
#define N_BAG  128
#define DXD    32
#define DYD    10
#define M_COMP 2048
#define MTILES (M_COMP / 16)   // 128 m-tiles
#define NTILES (N_BAG / 16)    // 8 n-tiles

typedef __attribute__((ext_vector_type(8))) short short8v;   // 8 bf16 (4 VGPRs)
typedef __attribute__((ext_vector_type(4))) float f32x4;

static __device__ __forceinline__ unsigned short f2bf_rne(float f) {
    unsigned int u = __float_as_uint(f);
    u += 0x7FFFu + ((u >> 16) & 1u);   // round-to-nearest-even (finite inputs only)
    return (unsigned short)(u >> 16);
}
static __device__ __forceinline__ float bf2f(unsigned short h) {
    return __uint_as_float(((unsigned int)h) << 16);
}
static __device__ __forceinline__ float fast_exp2(float x) {
#if __has_builtin(__builtin_amdgcn_exp2f)
    return __builtin_amdgcn_exp2f(x);
#else
    return __expf(x * 0.6931471805599453f);
#endif
}

// ---------------- prep: per-m fragments of B' = -2*c_x (bf16 hi/lo), b2, yv2 padded ------
// B fragment order (our own pi, consistent with A staging): tile mt, lane l = 16*g + (m&15),
// elem j <-> k = 8*g + j.
__global__ void prep_kernel(const float* __restrict__ c_x, const float* __restrict__ c_y,
                            float* __restrict__ b2, float* __restrict__ yv2p,
                            short8v* __restrict__ Bh, short8v* __restrict__ Bl) {
    int m = blockIdx.x * blockDim.x + threadIdx.x;
    if (m >= M_COMP) return;
    float cx[DXD];
    float s = 0.f;
#pragma unroll
    for (int j = 0; j < DXD / 4; ++j) {
        float4 v = ((const float4*)(c_x + (size_t)m * DXD))[j];
        cx[4 * j + 0] = v.x; cx[4 * j + 1] = v.y; cx[4 * j + 2] = v.z; cx[4 * j + 3] = v.w;
        s = fmaf(v.x, v.x, s); s = fmaf(v.y, v.y, s); s = fmaf(v.z, v.z, s); s = fmaf(v.w, v.w, s);
    }
    b2[m] = s;
    int mt = m >> 4, r = m & 15;
#pragma unroll
    for (int g = 0; g < 4; ++g) {
        short8v hv, lv;
#pragma unroll
        for (int j = 0; j < 8; ++j) {
            float val = -2.0f * cx[8 * g + j];
            unsigned short h = f2bf_rne(val);
            float lo = val - bf2f(h);
            hv[j] = (short)h;
            lv[j] = (short)f2bf_rne(lo);
        }
        Bh[mt * 64 + g * 16 + r] = hv;
        Bl[mt * 64 + g * 16 + r] = lv;
    }
    // yv2 padded to 12 floats/row for aligned float4 loads
    float cy[DYD], ny = 0.f;
#pragma unroll
    for (int d = 0; d < DYD; ++d) { cy[d] = c_y[(size_t)m * DYD + d]; ny = fmaf(cy[d], cy[d], ny); }
    float inv = 1.0f / ny;
#pragma unroll
    for (int d = 0; d < DYD; ++d) yv2p[(size_t)m * 12 + d] = cy[d] * cy[d] * inv;
    yv2p[(size_t)m * 12 + 10] = 0.f;
    yv2p[(size_t)m * 12 + 11] = 0.f;
}

// ---------------- main: (b, m-chunk) -> ow[b][m] = comp_w[m]/N * sum_n K^2 ---------------
__global__ __launch_bounds__(256, 3) void main_kernel(
    const float* __restrict__ X,        // (BS, N_BAG, DXD)
    const float* __restrict__ sig_p,    // scalar
    const float* __restrict__ comp_w,   // (M_COMP,)
    const float* __restrict__ b2,       // (M_COMP,)
    const short8v* __restrict__ Bh,     // (MTILES*64,)
    const short8v* __restrict__ Bl,
    float* __restrict__ ow)             // (BS, M_COMP)
{
    __shared__ short8v XhiF[NTILES][64];   // A fragments, hi plane (8 KB)
    __shared__ short8v XloF[NTILES][64];   // lo plane (8 KB)
    __shared__ float   a2part[N_BAG][4];
    __shared__ float   a2buf[N_BAG];

    const int tid   = threadIdx.x;
    const int b     = blockIdx.x >> 2;
    const int chunk = blockIdx.x & 3;

    // ---- stage X[b] as bf16 hi/lo fragments + row norms ----
#pragma unroll
    for (int c = tid; c < 512; c += 256) {
        int n = c >> 2, g = c & 3;
        const float4* Xr = (const float4*)(X + ((size_t)(b * N_BAG + n) * DXD + 8 * g));
        float4 v0 = Xr[0], v1 = Xr[1];
        float vals[8] = {v0.x, v0.y, v0.z, v0.w, v1.x, v1.y, v1.z, v1.w};
        float s = 0.f;
        short8v hv, lv;
#pragma unroll
        for (int j = 0; j < 8; ++j) {
            s = fmaf(vals[j], vals[j], s);
            unsigned short h = f2bf_rne(vals[j]);
            float lo = vals[j] - bf2f(h);
            hv[j] = (short)h;
            lv[j] = (short)f2bf_rne(lo);
        }
        XhiF[n >> 4][g * 16 + (n & 15)] = hv;
        XloF[n >> 4][g * 16 + (n & 15)] = lv;
        a2part[n][g] = s;
    }
    __syncthreads();
    if (tid < N_BAG)
        a2buf[tid] = a2part[tid][0] + a2part[tid][1] + a2part[tid][2] + a2part[tid][3];
    __syncthreads();

    // ---- per-wave: A fragments + a2 fragments into registers ----
    const int lane = tid & 63, wv = tid >> 6;
    short8v Ah[NTILES], Al[NTILES];
    f32x4   a2f[NTILES];
    const int rowg = (lane >> 4) * 4;   // C/D: row = (lane>>4)*4 + reg   [m89 verified]
    const int col  = lane & 15;         // C/D: col = lane & 15
#pragma unroll
    for (int t = 0; t < NTILES; ++t) {
        Ah[t]  = XhiF[t][lane];
        Al[t]  = XloF[t][lane];
        a2f[t] = *(const f32x4*)&a2buf[t * 16 + rowg];
    }

    const float sgm = fmaxf(sig_p[0], 1e-3f);
    const float c2  = -1.4426950408889634f / (sgm * sgm);   // -log2(e)/sigma^2

    for (int i = 0; i < 8; ++i) {
        const int mt = chunk * 32 + wv * 8 + i;
        short8v Bhv = Bh[mt * 64 + lane];
        short8v Blv = Bl[mt * 64 + lane];
        const int m = mt * 16 + col;
        const float b2c = b2[m];
        const float cw  = comp_w[m] * (1.0f / N_BAG);
        float csum = 0.f;
#pragma unroll
        for (int t = 0; t < NTILES; ++t) {
            f32x4 acc = a2f[t] + b2c;   // seed C with a2[row] + b2[col]
            acc = __builtin_amdgcn_mfma_f32_16x16x32_bf16(Ah[t], Bhv, acc, 0, 0, 0);
            acc = __builtin_amdgcn_mfma_f32_16x16x32_bf16(Ah[t], Blv, acc, 0, 0, 0);
            acc = __builtin_amdgcn_mfma_f32_16x16x32_bf16(Al[t], Bhv, acc, 0, 0, 0);
            // acc[r] = d2 for (row = t*16 + rowg + r, col = m). K^2 = 2^(d2 * c2), clamped d2>=0
#pragma unroll
            for (int r = 0; r < 4; ++r)
                csum += fast_exp2(fminf(acc[r] * c2, 0.f));
        }
        csum += __shfl_xor(csum, 16, 64);
        csum += __shfl_xor(csum, 32, 64);
        if (lane < 16) ow[(size_t)b * M_COMP + m] = csum * cw;
    }
}

// ---------------- final: per-b normalize + project through yv2 ---------------------------
__global__ __launch_bounds__(256) void final_kernel(const float* __restrict__ ow,
                                                    const float* __restrict__ yv2p,
                                                    float* __restrict__ out) {
    __shared__ float red[4][DYD + 1];
    __shared__ float sm[DYD + 1];
    const int b = blockIdx.x, tid = threadIdx.x;
    const int lane = tid & 63, wv = tid >> 6;

    float ps[DYD + 1];
#pragma unroll
    for (int v = 0; v <= DYD; ++v) ps[v] = 0.f;

    const int m0 = tid * 8;
    f32x4 o0 = *(const f32x4*)(ow + (size_t)b * M_COMP + m0);
    f32x4 o1 = *(const f32x4*)(ow + (size_t)b * M_COMP + m0 + 4);
    float w8[8] = {o0.x, o0.y, o0.z, o0.w, o1.x, o1.y, o1.z, o1.w};
#pragma unroll
    for (int u = 0; u < 8; ++u) {
        float w = w8[u];
        const f32x4* Y = (const f32x4*)(yv2p + (size_t)(m0 + u) * 12);
        f32x4 y0 = Y[0], y1 = Y[1], y2 = Y[2];
        ps[0] += w;
        ps[1] = fmaf(w, y0.x, ps[1]); ps[2]  = fmaf(w, y0.y, ps[2]);
        ps[3] = fmaf(w, y0.z, ps[3]); ps[4]  = fmaf(w, y0.w, ps[4]);
        ps[5] = fmaf(w, y1.x, ps[5]); ps[6]  = fmaf(w, y1.y, ps[6]);
        ps[7] = fmaf(w, y1.z, ps[7]); ps[8]  = fmaf(w, y1.w, ps[8]);
        ps[9] = fmaf(w, y2.x, ps[9]); ps[10] = fmaf(w, y2.y, ps[10]);
    }
#pragma unroll
    for (int v = 0; v <= DYD; ++v) {
        float x = ps[v];
#pragma unroll
        for (int off = 32; off > 0; off >>= 1) x += __shfl_down(x, off, 64);
        if (lane == 0) red[wv][v] = x;
    }
    __syncthreads();
    if (tid <= DYD) sm[tid] = red[0][tid] + red[1][tid] + red[2][tid] + red[3][tid];
    __syncthreads();
    if (tid < DYD) {
        float d = sm[0];
        d = (d == 0.f) ? 1e-16f : d;
        out[(size_t)b * DYD + tid] = sm[1 + tid] / d;
    }
}

extern "C" void kernel_launch(void* const* d_in, const int* in_sizes, int n_in,
                              void* d_out, int out_size, void* d_ws, size_t ws_size,
                              hipStream_t stream) {
    const float* X      = (const float*)d_in[0];  // (256,128,32)
    const float* sigma  = (const float*)d_in[1];  // scalar
    const float* c_x    = (const float*)d_in[2];  // (2048,32)
    const float* c_y    = (const float*)d_in[3];  // (2048,10)
    const float* comp_w = (const float*)d_in[4];  // (2048,)
    float*       out    = (float*)d_out;          // (256,10)

    float* wsf  = (float*)d_ws;
    float* ow   = wsf;                        // 256*2048            = 524288 floats
    float* b2   = wsf + 524288;               // 2048
    float* yv2p = wsf + 526336;               // 2048*12             = 24576
    short8v* Bh = (short8v*)(wsf + 550912);   // 128*64 short8v      = 32768 float-slots
    short8v* Bl = (short8v*)(wsf + 583680);   // same                (end: 616448 floats)

    prep_kernel<<<M_COMP / 256, 256, 0, stream>>>(c_x, c_y, b2, yv2p, Bh, Bl);
    main_kernel<<<BS * 4, 256, 0, stream>>>(X, sigma, comp_w, b2, Bh, Bl, ow);
    final_kernel<<<BS, 256, 0, stream>>>(ow, yv2p, out);
}

// Round 3
// 33.532 us; speedup vs baseline: 2.3359x; 1.0572x over previous
//
#include <hip/hip_runtime.h>

// Problem dims (fixed by setup_inputs)
#define BS     256
#define N_BAG  128
#define DXD    32
#define DYD    10
#define M_COMP 2048
#define MTILES (M_COMP / 16)   // 128 m-tiles
#define NTILES (N_BAG / 16)    // 8 n-tiles

typedef __attribute__((ext_vector_type(8))) short short8v;   // 8 bf16 (4 VGPRs)
typedef __attribute__((ext_vector_type(4))) float f32x4;

static __device__ __forceinline__ unsigned short f2bf_rne(float f) {
    unsigned int u = __float_as_uint(f);
    u += 0x7FFFu + ((u >> 16) & 1u);   // round-to-nearest-even (finite inputs only)
    return (unsigned short)(u >> 16);
}
static __device__ __forceinline__ float bf2f(unsigned short h) {
    return __uint_as_float(((unsigned int)h) << 16);
}
static __device__ __forceinline__ float fast_exp2(float x) {
#if __has_builtin(__builtin_amdgcn_exp2f)
    return __builtin_amdgcn_exp2f(x);
#else
    return __expf(x * 0.6931471805599453f);
#endif
}

// ---------------- prep: per-m fragments of B' = -2*c_x (bf16 hi/lo), b2, yv2 padded ------
// Fragment order pi (shared with A staging): tile mt, lane l = 16*g + (m&15), elem j <-> k = 8*g + j.
__global__ void prep_kernel(const float* __restrict__ c_x, const float* __restrict__ c_y,
                            float* __restrict__ b2, float* __restrict__ yv2p,
                            short8v* __restrict__ Bh, short8v* __restrict__ Bl) {
    int m = blockIdx.x * blockDim.x + threadIdx.x;
    if (m >= M_COMP) return;
    float cx[DXD];
    float s = 0.f;
#pragma unroll
    for (int j = 0; j < DXD / 4; ++j) {
        float4 v = ((const float4*)(c_x + (size_t)m * DXD))[j];
        cx[4 * j + 0] = v.x; cx[4 * j + 1] = v.y; cx[4 * j + 2] = v.z; cx[4 * j + 3] = v.w;
        s = fmaf(v.x, v.x, s); s = fmaf(v.y, v.y, s); s = fmaf(v.z, v.z, s); s = fmaf(v.w, v.w, s);
    }
    b2[m] = s;
    int mt = m >> 4, r = m & 15;
#pragma unroll
    for (int g = 0; g < 4; ++g) {
        short8v hv, lv;
#pragma unroll
        for (int j = 0; j < 8; ++j) {
            float val = -2.0f * cx[8 * g + j];
            unsigned short h = f2bf_rne(val);
            float lo = val - bf2f(h);
            hv[j] = (short)h;
            lv[j] = (short)f2bf_rne(lo);
        }
        Bh[mt * 64 + g * 16 + r] = hv;
        Bl[mt * 64 + g * 16 + r] = lv;
    }
    // yv2 padded to 12 floats/row for aligned float4 loads
    float cy[DYD], ny = 0.f;
#pragma unroll
    for (int d = 0; d < DYD; ++d) { cy[d] = c_y[(size_t)m * DYD + d]; ny = fmaf(cy[d], cy[d], ny); }
    float inv = 1.0f / ny;
#pragma unroll
    for (int d = 0; d < DYD; ++d) yv2p[(size_t)m * 12 + d] = cy[d] * cy[d] * inv;
    yv2p[(size_t)m * 12 + 10] = 0.f;
    yv2p[(size_t)m * 12 + 11] = 0.f;
}

// ---------------- main: (b, m-chunk) -> 11 partials: [wsum, probs(10)] -------------------
__global__ __launch_bounds__(256, 4) void main_kernel(
    const float* __restrict__ X,        // (BS, N_BAG, DXD)
    const float* __restrict__ sig_p,    // scalar
    const float* __restrict__ comp_w,   // (M_COMP,)
    const float* __restrict__ b2,       // (M_COMP,)
    const short8v* __restrict__ Bh,     // (MTILES*64,)
    const short8v* __restrict__ Bl,
    const float* __restrict__ yv2p,     // (M_COMP, 12)
    float* __restrict__ part)           // (BS*4, 16): [0]=wsum, [1..10]=probs partials
{
    __shared__ short8v XhiF[NTILES][64];   // A fragments, hi plane (8 KB)
    __shared__ float   a2part[N_BAG][4];
    __shared__ float   a2buf[N_BAG];
    __shared__ float   red[4][DYD + 1];

    const int tid   = threadIdx.x;
    const int b     = blockIdx.x >> 2;
    const int chunk = blockIdx.x & 3;

    // ---- stage X[b] as bf16-hi fragments + row norms (fp32 exact) ----
#pragma unroll
    for (int c = tid; c < 512; c += 256) {
        int n = c >> 2, g = c & 3;
        const float4* Xr = (const float4*)(X + ((size_t)(b * N_BAG + n) * DXD + 8 * g));
        float4 v0 = Xr[0], v1 = Xr[1];
        float vals[8] = {v0.x, v0.y, v0.z, v0.w, v1.x, v1.y, v1.z, v1.w};
        float s = 0.f;
        short8v hv;
#pragma unroll
        for (int j = 0; j < 8; ++j) {
            s = fmaf(vals[j], vals[j], s);
            hv[j] = (short)f2bf_rne(vals[j]);
        }
        XhiF[n >> 4][g * 16 + (n & 15)] = hv;
        a2part[n][g] = s;
    }
    __syncthreads();
    if (tid < N_BAG)
        a2buf[tid] = a2part[tid][0] + a2part[tid][1] + a2part[tid][2] + a2part[tid][3];
    __syncthreads();

    // ---- per-wave: A fragments + a2 fragments into registers ----
    const int lane = tid & 63, wv = tid >> 6;
    short8v Ah[NTILES];
    f32x4   a2f[NTILES];
    const int rowg = (lane >> 4) * 4;   // C/D: row = (lane>>4)*4 + reg   [m89 verified]
    const int col  = lane & 15;         // C/D: col = lane & 15
#pragma unroll
    for (int t = 0; t < NTILES; ++t) {
        Ah[t]  = XhiF[t][lane];
        a2f[t] = *(const f32x4*)&a2buf[t * 16 + rowg];
    }

    const float sgm = fmaxf(sig_p[0], 1e-3f);
    const float c2  = -1.4426950408889634f / (sgm * sgm);   // -log2(e)/sigma^2  (K^2 exponent)

    float acc11[DYD + 1];
#pragma unroll
    for (int v = 0; v <= DYD; ++v) acc11[v] = 0.f;

    for (int i = 0; i < 8; ++i) {
        const int mt = chunk * 32 + wv * 8 + i;
        short8v Bhv = Bh[mt * 64 + lane];
        short8v Blv = Bl[mt * 64 + lane];
        const int m = mt * 16 + col;
        const float b2c = b2[m];
        const float cw  = comp_w[m] * (1.0f / N_BAG);
        float csum = 0.f;
#pragma unroll
        for (int t = 0; t < NTILES; ++t) {
            f32x4 acc = a2f[t] + b2c;   // seed C with a2[row] + b2[col]
            acc = __builtin_amdgcn_mfma_f32_16x16x32_bf16(Ah[t], Bhv, acc, 0, 0, 0);
            acc = __builtin_amdgcn_mfma_f32_16x16x32_bf16(Ah[t], Blv, acc, 0, 0, 0);
            // acc[r] = d2(row = t*16+rowg+r, col = m); K^2 = 2^(d2*c2), clamped d2 >= 0
#pragma unroll
            for (int r = 0; r < 4; ++r)
                csum += fast_exp2(fminf(acc[r] * c2, 0.f));
        }
        csum += __shfl_xor(csum, 16, 64);
        csum += __shfl_xor(csum, 32, 64);
        if (lane < 16) {   // one lane per column owns this m's contribution
            const float owm = csum * cw;
            const f32x4* Y = (const f32x4*)(yv2p + (size_t)m * 12);
            f32x4 y0 = Y[0], y1 = Y[1], y2 = Y[2];
            acc11[0] += owm;
            acc11[1] = fmaf(owm, y0.x, acc11[1]); acc11[2]  = fmaf(owm, y0.y, acc11[2]);
            acc11[3] = fmaf(owm, y0.z, acc11[3]); acc11[4]  = fmaf(owm, y0.w, acc11[4]);
            acc11[5] = fmaf(owm, y1.x, acc11[5]); acc11[6]  = fmaf(owm, y1.y, acc11[6]);
            acc11[7] = fmaf(owm, y1.z, acc11[7]); acc11[8]  = fmaf(owm, y1.w, acc11[8]);
            acc11[9] = fmaf(owm, y2.x, acc11[9]); acc11[10] = fmaf(owm, y2.y, acc11[10]);
        }
    }

    // ---- block reduce 11 values (lanes >= 16 hold zeros) ----
#pragma unroll
    for (int v = 0; v <= DYD; ++v) {
        float x = acc11[v];
#pragma unroll
        for (int off = 32; off > 0; off >>= 1) x += __shfl_down(x, off, 64);
        if (lane == 0) red[wv][v] = x;
    }
    __syncthreads();
    if (tid <= DYD)
        part[blockIdx.x * 16 + tid] = red[0][tid] + red[1][tid] + red[2][tid] + red[3][tid];
}

// ---------------- combine: 1 block; thread b sums 4 chunk-partials, normalizes -----------
__global__ __launch_bounds__(256) void combine_kernel(const float* __restrict__ part,
                                                      float* __restrict__ out) {
    const int b = threadIdx.x;
    const float* p = part + (size_t)b * 4 * 16;
    float wsum = p[0] + p[16] + p[32] + p[48];
    wsum = (wsum == 0.f) ? 1e-16f : wsum;
    const float invd = 1.0f / wsum;
#pragma unroll
    for (int d = 0; d < DYD; ++d) {
        float s = p[1 + d] + p[16 + 1 + d] + p[32 + 1 + d] + p[48 + 1 + d];
        out[(size_t)b * DYD + d] = s * invd;
    }
}

extern "C" void kernel_launch(void* const* d_in, const int* in_sizes, int n_in,
                              void* d_out, int out_size, void* d_ws, size_t ws_size,
                              hipStream_t stream) {
    const float* X      = (const float*)d_in[0];  // (256,128,32)
    const float* sigma  = (const float*)d_in[1];  // scalar
    const float* c_x    = (const float*)d_in[2];  // (2048,32)
    const float* c_y    = (const float*)d_in[3];  // (2048,10)
    const float* comp_w = (const float*)d_in[4];  // (2048,)
    float*       out    = (float*)d_out;          // (256,10)

    float* wsf  = (float*)d_ws;
    float* part = wsf;                        // 1024*16 = 16384 floats
    float* b2   = wsf + 16384;                // 2048
    float* yv2p = wsf + 18432;                // 2048*12 = 24576
    short8v* Bh = (short8v*)(wsf + 43008);    // 128*64 short8v = 32768 float-slots
    short8v* Bl = (short8v*)(wsf + 75776);    // same (end: 108544 floats ~ 434 KB)

    prep_kernel<<<M_COMP / 256, 256, 0, stream>>>(c_x, c_y, b2, yv2p, Bh, Bl);
    main_kernel<<<BS * 4, 256, 0, stream>>>(X, sigma, comp_w, b2, Bh, Bl, yv2p, part);
    combine_kernel<<<1, 256, 0, stream>>>(part, out);
}

// Round 4
// 25.680 us; speedup vs baseline: 3.0501x; 1.3058x over previous
//
#include <hip/hip_runtime.h>
#include <hip/hip_bf16.h>

// Problem dims (fixed by setup_inputs)
#define BS     256
#define N_BAG  128
#define DXD    32
#define DYD    10
#define M_COMP 2048
#define NTILES 8              // n-tiles (128/16)
#define WAVES  16             // block = 1024 threads
#define MT_PW  8              // m-tiles per wave (128 tiles / 16 waves)

typedef __attribute__((ext_vector_type(8))) short short8v;   // 8 bf16 (4 VGPRs)
typedef __attribute__((ext_vector_type(4))) float f32x4;

static __device__ __forceinline__ unsigned int pkbf(float a, float b) {
    // RNE pack of two f32 -> 2x bf16 in one u32 (compiler emits v_cvt_pk_bf16_f32)
    unsigned short ha = __bfloat16_as_ushort(__float2bfloat16(a));
    unsigned short hb = __bfloat16_as_ushort(__float2bfloat16(b));
    return (unsigned int)ha | ((unsigned int)hb << 16);
}
static __device__ __forceinline__ float fast_exp2(float x) {
#if __has_builtin(__builtin_amdgcn_exp2f)
    return __builtin_amdgcn_exp2f(x);
#else
    return __expf(x * 0.6931471805599453f);
#endif
}

// One block per batch row b. 16 waves; wave wv owns m-tiles [wv*8, wv*8+8).
// d2 = a2 + b2 - 2*dot via MFMA seeded with -a2/2 on raw-c_x bf16 operands:
//   acc = dot - a2/2 ;  e = cp*acc + cb = -d2*log2e/sigma^2 ;  K^2 = 2^min(e,0)
__global__ __launch_bounds__(1024, 4) void fused_kernel(
    const float* __restrict__ X,        // (BS, N_BAG, DXD)
    const float* __restrict__ sig_p,    // scalar
    const float* __restrict__ c_x,      // (M_COMP, DXD)
    const float* __restrict__ c_y,      // (M_COMP, DYD)
    const float* __restrict__ comp_w,   // (M_COMP,)
    float* __restrict__ out)            // (BS, DYD)
{
    __shared__ short8v XhiF[NTILES][64];       // A fragments (8 KB)
    __shared__ float   a2part[N_BAG][4];
    __shared__ float   a2buf[N_BAG];           // -0.5 * ||x_n||^2
    __shared__ float   red[WAVES][DYD + 2];
    __shared__ float   sm[DYD + 1];

    const int tid = threadIdx.x;
    const int b   = blockIdx.x;

    // ---- stage X[b] as bf16 fragments + row norms (fp32 exact) ----
    if (tid < 512) {
        const int n = tid >> 2, g4 = tid & 3;
        const float4* Xr = (const float4*)(X + ((size_t)(b * N_BAG + n) * DXD + 8 * g4));
        float4 v0 = Xr[0], v1 = Xr[1];
        float s = 0.f;
        s = fmaf(v0.x, v0.x, s); s = fmaf(v0.y, v0.y, s);
        s = fmaf(v0.z, v0.z, s); s = fmaf(v0.w, v0.w, s);
        s = fmaf(v1.x, v1.x, s); s = fmaf(v1.y, v1.y, s);
        s = fmaf(v1.z, v1.z, s); s = fmaf(v1.w, v1.w, s);
        union { unsigned int u[4]; short8v s8; } cv;
        cv.u[0] = pkbf(v0.x, v0.y); cv.u[1] = pkbf(v0.z, v0.w);
        cv.u[2] = pkbf(v1.x, v1.y); cv.u[3] = pkbf(v1.z, v1.w);
        XhiF[n >> 4][g4 * 16 + (n & 15)] = cv.s8;
        a2part[n][g4] = s;
    }
    __syncthreads();
    if (tid < N_BAG)
        a2buf[tid] = -0.5f * (a2part[tid][0] + a2part[tid][1] +
                              a2part[tid][2] + a2part[tid][3]);
    __syncthreads();

    // ---- per-wave register state ----
    const int lane = tid & 63, wv = tid >> 6;
    const int r = lane & 15, gq = lane >> 4;
    const int rowg = gq * 4;                    // C/D: row=(lane>>4)*4+reg, col=lane&15 [m89]
    short8v Ah[NTILES];
    f32x4   a2f[NTILES];
#pragma unroll
    for (int t = 0; t < NTILES; ++t) {
        Ah[t]  = XhiF[t][lane];
        a2f[t] = *(const f32x4*)&a2buf[t * 16 + rowg];
    }

    const float sgm = fmaxf(sig_p[0], 1e-3f);
    const float cp  = 2.0f * 1.4426950408889634f / (sgm * sgm);  // 2*log2(e)/sigma^2

    float acc11[DYD + 1];
#pragma unroll
    for (int v = 0; v <= DYD; ++v) acc11[v] = 0.f;

    const int    m_base = wv * (MT_PW * 16) + r;          // m for tile i = m_base + 16*i
    const float* cxp    = c_x + (size_t)m_base * DXD + 8 * gq;

    float4 p0 = *(const float4*)(cxp);
    float4 p1 = *(const float4*)(cxp + 4);

#pragma unroll
    for (int i = 0; i < MT_PW; ++i) {
        const int m = m_base + 16 * i;
        // prefetch next c_x tile (static predicate: fully unrolled)
        float4 q0, q1;
        if (i + 1 < MT_PW) {
            q0 = *(const float4*)(cxp + (i + 1) * 16 * DXD);
            q1 = *(const float4*)(cxp + (i + 1) * 16 * DXD + 4);
        }
        const float cw = comp_w[m] * (1.0f / N_BAG);
        float cy[DYD];
        if (lane < 16) {
#pragma unroll
            for (int d = 0; d < DYD; ++d) cy[d] = c_y[(size_t)m * DYD + d];
        }
        // convert B tile to bf16 + in-wave b2 (sum of squares over k)
        union { unsigned int u[4]; short8v s8; } bc;
        bc.u[0] = pkbf(p0.x, p0.y); bc.u[1] = pkbf(p0.z, p0.w);
        bc.u[2] = pkbf(p1.x, p1.y); bc.u[3] = pkbf(p1.z, p1.w);
        float s = 0.f;
        s = fmaf(p0.x, p0.x, s); s = fmaf(p0.y, p0.y, s);
        s = fmaf(p0.z, p0.z, s); s = fmaf(p0.w, p0.w, s);
        s = fmaf(p1.x, p1.x, s); s = fmaf(p1.y, p1.y, s);
        s = fmaf(p1.z, p1.z, s); s = fmaf(p1.w, p1.w, s);
        s += __shfl_xor(s, 16, 64);
        s += __shfl_xor(s, 32, 64);              // full b2[m] in every lane
        const float cb = -0.5f * cp * s;

        float csum = 0.f;
#pragma unroll
        for (int t = 0; t < NTILES; ++t) {
            f32x4 acc = __builtin_amdgcn_mfma_f32_16x16x32_bf16(Ah[t], bc.s8, a2f[t], 0, 0, 0);
#pragma unroll
            for (int rr = 0; rr < 4; ++rr) {
                float e = fminf(fmaf(cp, acc[rr], cb), 0.f);
                csum += fast_exp2(e);            // = K^2, clamped d2 >= 0
            }
        }
        csum += __shfl_xor(csum, 16, 64);
        csum += __shfl_xor(csum, 32, 64);        // sum over all 128 n

        if (lane < 16) {                         // column owner for this m
            float ny = 0.f;
#pragma unroll
            for (int d = 0; d < DYD; ++d) ny = fmaf(cy[d], cy[d], ny);
            const float owm = csum * cw;
            const float yw  = owm * __builtin_amdgcn_rcpf(ny);
            acc11[0] += owm;
#pragma unroll
            for (int d = 0; d < DYD; ++d)
                acc11[1 + d] = fmaf(cy[d] * cy[d], yw, acc11[1 + d]);
        }
        p0 = q0; p1 = q1;
    }

    // ---- block reduce 11 values (lanes >= 16 hold zeros) ----
#pragma unroll
    for (int v = 0; v <= DYD; ++v) {
        float x = acc11[v];
#pragma unroll
        for (int off = 32; off > 0; off >>= 1) x += __shfl_down(x, off, 64);
        if (lane == 0) red[wv][v] = x;
    }
    __syncthreads();
    if (tid <= DYD) {
        float ssum = 0.f;
#pragma unroll
        for (int w = 0; w < WAVES; ++w) ssum += red[w][tid];
        sm[tid] = ssum;
    }
    __syncthreads();
    if (tid < DYD) {
        float d = sm[0];
        d = (d == 0.f) ? 1e-16f : d;
        out[(size_t)b * DYD + tid] = sm[1 + tid] / d;
    }
}

extern "C" void kernel_launch(void* const* d_in, const int* in_sizes, int n_in,
                              void* d_out, int out_size, void* d_ws, size_t ws_size,
                              hipStream_t stream) {
    const float* X      = (const float*)d_in[0];  // (256,128,32)
    const float* sigma  = (const float*)d_in[1];  // scalar
    const float* c_x    = (const float*)d_in[2];  // (2048,32)
    const float* c_y    = (const float*)d_in[3];  // (2048,10)
    const float* comp_w = (const float*)d_in[4];  // (2048,)
    float*       out    = (float*)d_out;          // (256,10)

    fused_kernel<<<BS, 1024, 0, stream>>>(X, sigma, c_x, c_y, comp_w, out);
}